// Round 3
// baseline (135.252 us; speedup 1.0000x reference)
//
#include <hip/hip_runtime.h>
#include <hip/hip_bf16.h>

typedef __bf16 bf16x8 __attribute__((ext_vector_type(8)));
typedef float f32x4 __attribute__((ext_vector_type(4)));

#define HDIM 4096
#define EDIM 64
#define KBLK 128      // 4096 / 32
#define KSPLIT 4
#define NCHUNK 16     // per wave: 16 chunks x 64 floats (= 2 kb-steps of 32)

// ---------------------------------------------------------------------------
// Kernel 1: coalesced repack of W into MFMA B-frag layout (UNnormalized bf16)
// + per-block per-column sum-of-squares partials (fp32).
// Wp element index for B[k][e]: nt=e>>4, col=e&15, kb=k>>5, g=(k>>3)&3, j=k&7
//   -> ((nt*KBLK + kb)*64 + col + 16*g)*8 + j
// ---------------------------------------------------------------------------
__global__ __launch_bounds__(256) void pack_w_kernel(const float* __restrict__ W,
                                                     __bf16* __restrict__ Wp,
                                                     float* __restrict__ partial) {
  const int b = blockIdx.x;        // 64 blocks x 64 rows of W
  const int t = threadIdx.x;
  const int e = t & 63;
  const int nt = e >> 4, col = e & 15;
  __shared__ float red[256];
  float s = 0.f;
  const int base = b * 64 * 64;
#pragma unroll
  for (int i = 0; i < 16; ++i) {
    int flat = base + i * 256 + t;         // coalesced: 4 rows per pass
    float v = W[flat];
    s = fmaf(v, v, s);
    int r = flat >> 6;                     // k index
    int kb = r >> 5, g = (r >> 3) & 3, j = r & 7;
    Wp[(size_t)((nt * KBLK + kb) * 64 + col + 16 * g) * 8 + j] = (__bf16)v;
  }
  red[t] = s;
  __syncthreads();
  if (t < 64)
    partial[b * 64 + t] = red[t] + red[t + 64] + red[t + 128] + red[t + 192];
}

// ---------------------------------------------------------------------------
// Kernel 2: fused norm_h @ (Wp * invw) + sigmoid/gate epilogue.
// Block = 4 waves, 16 rows, K-split x4 (wave w owns K-slice w).
// A path: coalesced global->reg (full 64B lines) -> wave-private XOR-swizzled
// LDS tile [2][16][128B] -> ds_read_b128 frags. No barriers in main loop.
// C/D layout (m89): lane l, reg r -> row (l>>4)*4+r, col l&15.
// ---------------------------------------------------------------------------
__global__ __launch_bounds__(256, 4) void gate_main_kernel(
    const float* __restrict__ H, const __bf16* __restrict__ Wp,
    const float* __restrict__ G, const float* __restrict__ partial,
    float* __restrict__ out, size_t third) {
  const int lane = threadIdx.x & 63;
  const int w = threadIdx.x >> 6;        // wave id = K-slice id
  const int m = lane & 15;
  const int g = lane >> 4;
  const int row0 = blockIdx.x * 16;

  __shared__ __align__(16) float lds_stage[KSPLIT][1024];  // 4 KB per wave
  __shared__ float lds_acc[16][KSPLIT][64];
  __shared__ float lds_ssq[KSPLIT][16];

  // ---- W column inv-norm from pack partials (L2-hot, hidden at start)
  float cs = 0.f;
  {
    const float* pp = partial + (w * 16 + m);
#pragma unroll 8
    for (int i = 0; i < 64; ++i) cs += pp[i * 64];
  }
  const float invw = 1.0f / fmaxf(sqrtf(cs), 1e-12f);

  // ---- staging geometry (wave-private)
  float* sb = lds_stage[w];
  const int sr = lane >> 2;              // staged row 0..15
  const int sq = lane & 3;               // quad within row
  const float* gsrc = H + (size_t)(row0 + sr) * HDIM + w * 1024 + sq * 4;

  int woff[4];
#pragma unroll
  for (int t = 0; t < 4; ++t) {
    int cb = sq * 16 + t * 64;           // byte within 256B row-chunk
    woff[t] = (cb >> 7) * 512 + sr * 32 + (((cb & 127) ^ ((sr & 7) << 4)) >> 2);
  }
  const int rb0 = m * 32 + ((( g * 32      ) ^ ((m & 7) << 4)) >> 2);
  const int rb1 = m * 32 + ((( g * 32 + 16 ) ^ ((m & 7) << 4)) >> 2);

  const bf16x8* bbase = reinterpret_cast<const bf16x8*>(Wp) + lane;
  const int kb0 = w * 32;

  f32x4 acc[4] = {};
  float ssq0 = 0.f, ssq1 = 0.f;

  float4 sreg[4];
#pragma unroll
  for (int t = 0; t < 4; ++t) sreg[t] = *(const float4*)(gsrc + t * 16);

  for (int c = 0; c < NCHUNK; ++c) {
    // commit staged chunk c to wave-private LDS
#pragma unroll
    for (int t = 0; t < 4; ++t) *(float4*)(sb + woff[t]) = sreg[t];
    // issue next chunk's coalesced loads (hidden under compute below)
    if (c + 1 < NCHUNK) {
      const float* gs = gsrc + (c + 1) * 64;
#pragma unroll
      for (int t = 0; t < 4; ++t) sreg[t] = *(const float4*)(gs + t * 16);
    }
#pragma unroll
    for (int s = 0; s < 2; ++s) {
      const int kb = kb0 + c * 2 + s;
      bf16x8 bfr[4];
#pragma unroll
      for (int nt = 0; nt < 4; ++nt)
        bfr[nt] = bbase[(size_t)(nt * KBLK + kb) * 64];

      float4 x0 = *(const float4*)(sb + s * 512 + rb0);
      float4 x1 = *(const float4*)(sb + s * 512 + rb1);

      bf16x8 af;
      af[0] = (__bf16)x0.x; af[1] = (__bf16)x0.y;
      af[2] = (__bf16)x0.z; af[3] = (__bf16)x0.w;
      af[4] = (__bf16)x1.x; af[5] = (__bf16)x1.y;
      af[6] = (__bf16)x1.z; af[7] = (__bf16)x1.w;

      ssq0 = fmaf(x0.x, x0.x, ssq0); ssq1 = fmaf(x0.y, x0.y, ssq1);
      ssq0 = fmaf(x0.z, x0.z, ssq0); ssq1 = fmaf(x0.w, x0.w, ssq1);
      ssq0 = fmaf(x1.x, x1.x, ssq0); ssq1 = fmaf(x1.y, x1.y, ssq1);
      ssq0 = fmaf(x1.z, x1.z, ssq0); ssq1 = fmaf(x1.w, x1.w, ssq1);

#pragma unroll
      for (int nt = 0; nt < 4; ++nt)
        acc[nt] = __builtin_amdgcn_mfma_f32_16x16x32_bf16(af, bfr[nt], acc[nt], 0, 0, 0);
    }
  }

  // ---- combine K-slices + epilogue
  float ssq = ssq0 + ssq1;
  ssq += __shfl_xor(ssq, 16, 64);
  ssq += __shfl_xor(ssq, 32, 64);

#pragma unroll
  for (int nt = 0; nt < 4; ++nt)
#pragma unroll
    for (int r = 0; r < 4; ++r) lds_acc[nt * 4 + r][w][lane] = acc[nt][r];
  if (g == 0) lds_ssq[w][m] = ssq;
  __syncthreads();

  {
    const int e = w * 16 + m;            // wave w owns cols [w*16, w*16+16)
    const float sg = 1.0f / (1.0f + __expf(-G[e]));
#pragma unroll
    for (int r = 0; r < 4; ++r) {
      const int rowi = g * 4 + r;
      float st = lds_ssq[0][rowi] + lds_ssq[1][rowi] +
                 lds_ssq[2][rowi] + lds_ssq[3][rowi];
      float invh = 1.0f / fmaxf(sqrtf(st), 1e-12f);
      float a = lds_acc[w * 4 + r][0][lane] + lds_acc[w * 4 + r][1][lane] +
                lds_acc[w * 4 + r][2][lane] + lds_acc[w * 4 + r][3][lane];
      float raw = a * invh * invw;
      float sig = 1.0f / (1.0f + __expf(-raw));
      size_t idx = (size_t)(row0 + rowi) * EDIM + e;
      out[idx] = raw;
      out[idx + third] = sig;
      out[idx + 2 * third] = fmaxf(sig - sg, 0.0f);
    }
  }
}

extern "C" void kernel_launch(void* const* d_in, const int* in_sizes, int n_in,
                              void* d_out, int out_size, void* d_ws, size_t ws_size,
                              hipStream_t stream) {
  const float* H = (const float*)d_in[0];   // [B*S, 4096]
  const float* W = (const float*)d_in[1];   // [4096, 64]
  const float* G = (const float*)d_in[2];   // [64]
  float* out = (float*)d_out;               // 3 x [B*S, 64] concatenated
  __bf16* Wp = (__bf16*)d_ws;               // 512 KB packed (unnormalized) W
  float* partial = (float*)((char*)d_ws + 512 * 1024);  // 64 blocks x 64 cols

  int rows = in_sizes[0] / HDIM;            // 16384
  size_t third = (size_t)out_size / 3;      // 1048576

  pack_w_kernel<<<64, 256, 0, stream>>>(W, Wp, partial);
  gate_main_kernel<<<rows / 16, 256, 0, stream>>>(H, Wp, G, partial, out, third);
}

// Round 4
// 89.700 us; speedup vs baseline: 1.5078x; 1.5078x over previous
//
#include <hip/hip_runtime.h>
#include <hip/hip_bf16.h>

typedef __bf16 bf16x8 __attribute__((ext_vector_type(8)));
typedef float f32x4 __attribute__((ext_vector_type(4)));

#define HDIM 4096
#define EDIM 64
#define KBLK 128      // 4096 / 32
#define NW 8          // waves per block = K-split factor
#define KBW (KBLK/NW) // 16 kb-steps per wave

// ---------------------------------------------------------------------------
// Kernel 1: coalesced repack of W into MFMA B-frag layout (UNnormalized bf16)
// + per-block per-column sum-of-squares partials (fp32).
// Wp element index for B[k][e]: nt=e>>4, col=e&15, kb=k>>5, g=(k>>3)&3, j=k&7
//   -> ((nt*KBLK + kb)*64 + col + 16*g)*8 + j
// ---------------------------------------------------------------------------
__global__ __launch_bounds__(256) void pack_w_kernel(const float* __restrict__ W,
                                                     __bf16* __restrict__ Wp,
                                                     float* __restrict__ partial) {
  const int b = blockIdx.x;        // 64 blocks x 64 rows of W
  const int t = threadIdx.x;
  const int e = t & 63;
  const int nt = e >> 4, col = e & 15;
  __shared__ float red[256];
  float s = 0.f;
  const int base = b * 64 * 64;
#pragma unroll
  for (int i = 0; i < 16; ++i) {
    int flat = base + i * 256 + t;         // coalesced: 4 rows per pass
    float v = W[flat];
    s = fmaf(v, v, s);
    int r = flat >> 6;                     // k index
    int kb = r >> 5, g = (r >> 3) & 3, j = r & 7;
    Wp[(size_t)((nt * KBLK + kb) * 64 + col + 16 * g) * 8 + j] = (__bf16)v;
  }
  red[t] = s;
  __syncthreads();
  if (t < 64)
    partial[b * 64 + t] = red[t] + red[t + 64] + red[t + 128] + red[t + 192];
}

// ---------------------------------------------------------------------------
// Kernel 2: fused norm_h @ (Wp * invw) + sigmoid/gate epilogue.
// Block = 8 waves (512 thr), 16 rows, K-split x8: wave w owns K-slice w
// (512 floats = 16 kb-steps). Direct global->reg A loads feeding MFMA
// (R1 dataflow — no LDS round-trip in the main loop). LDS used only for
// the final acc/ssq combine.
// Grid: rows/16 = 1024 blocks -> 4 blocks/CU = 32 waves/CU = 8/SIMD.
// A-frag: lane l holds h[row0+(l&15)][kb*32 + (l>>4)*8 + j]  (fp32->bf16).
// C/D layout (m89): lane l, reg r -> row (l>>4)*4+r, col l&15.
// Epilogue: lane = column, each wave stores FULL 256-B contiguous rows
// (fixes the 109 MB partial-line write amplification seen in R2).
// ---------------------------------------------------------------------------
__global__ __launch_bounds__(512, 6) void gate_main_kernel(
    const float* __restrict__ H, const __bf16* __restrict__ Wp,
    const float* __restrict__ G, const float* __restrict__ partial,
    float* __restrict__ out, size_t third) {
  const int lane = threadIdx.x & 63;
  const int w = threadIdx.x >> 6;        // wave id = K-slice id, 0..7
  const int m = lane & 15;
  const int g = lane >> 4;
  const int row0 = blockIdx.x * 16;

  __shared__ float lds_acc[16][NW][64];  // 32 KB: [frag][wave][lane]
  __shared__ float lds_ssq[NW][16];
  __shared__ float lds_invw[64];

  const int kb0 = w * KBW;
  const float* hp = H + (size_t)(row0 + m) * HDIM + kb0 * 32 + g * 8;
  const bf16x8* bbase = reinterpret_cast<const bf16x8*>(Wp) + lane;

  f32x4 acc[4] = {};
  float ssq0 = 0.f, ssq1 = 0.f;

#pragma unroll 4
  for (int i = 0; i < KBW; ++i) {
    float4 a0 = *reinterpret_cast<const float4*>(hp + (size_t)i * 32);
    float4 a1 = *reinterpret_cast<const float4*>(hp + (size_t)i * 32 + 4);

    bf16x8 bfr[4];
#pragma unroll
    for (int nt = 0; nt < 4; ++nt)
      bfr[nt] = bbase[(size_t)(nt * KBLK + kb0 + i) * 64];

    bf16x8 af;
    af[0] = (__bf16)a0.x; af[1] = (__bf16)a0.y;
    af[2] = (__bf16)a0.z; af[3] = (__bf16)a0.w;
    af[4] = (__bf16)a1.x; af[5] = (__bf16)a1.y;
    af[6] = (__bf16)a1.z; af[7] = (__bf16)a1.w;

    ssq0 = fmaf(a0.x, a0.x, ssq0); ssq1 = fmaf(a0.y, a0.y, ssq1);
    ssq0 = fmaf(a0.z, a0.z, ssq0); ssq1 = fmaf(a0.w, a0.w, ssq1);
    ssq0 = fmaf(a1.x, a1.x, ssq0); ssq1 = fmaf(a1.y, a1.y, ssq1);
    ssq0 = fmaf(a1.z, a1.z, ssq0); ssq1 = fmaf(a1.w, a1.w, ssq1);

#pragma unroll
    for (int nt = 0; nt < 4; ++nt)
      acc[nt] = __builtin_amdgcn_mfma_f32_16x16x32_bf16(af, bfr[nt], acc[nt], 0, 0, 0);
  }

  // per-row partial ssq for this K-slice: sum lanes {m, m+16, m+32, m+48}
  float ssq = ssq0 + ssq1;
  ssq += __shfl_xor(ssq, 16, 64);
  ssq += __shfl_xor(ssq, 32, 64);

#pragma unroll
  for (int nt = 0; nt < 4; ++nt)
#pragma unroll
    for (int r = 0; r < 4; ++r) lds_acc[nt * 4 + r][w][lane] = acc[nt][r];
  if (g == 0) lds_ssq[w][m] = ssq;

  // W-column inv-norms (off the critical startup path; waves 0-3 only)
  if (w < 4) {
    float cs = 0.f;
    const float* pp = partial + (w * 16 + m);
#pragma unroll 8
    for (int i = 0; i < 64; ++i) cs += pp[i * 64];
    if (g == 0) lds_invw[w * 16 + m] = 1.0f / fmaxf(sqrtf(cs), 1e-12f);
  }
  __syncthreads();

  // Epilogue: lane = output column e; wave w stores rows {2w, 2w+1} as
  // full 256-B contiguous stores per output.
  {
    const float invw = lds_invw[lane];
    const float sg = 1.0f / (1.0f + __expf(-G[lane]));
#pragma unroll
    for (int rr = 0; rr < 2; ++rr) {
      const int R = w * 2 + rr;
      float st = 0.f, a = 0.f;
      const int fr = (lane >> 4) * 4 + (R & 3);
      const int i2 = ((R & 12) << 2) + (lane & 15);
#pragma unroll
      for (int ws = 0; ws < NW; ++ws) {
        st += lds_ssq[ws][R];
        a += lds_acc[fr][ws][i2];
      }
      float invh = 1.0f / fmaxf(sqrtf(st), 1e-12f);
      float raw = a * invh * invw;
      float sig = 1.0f / (1.0f + __expf(-raw));
      size_t idx = (size_t)(row0 + R) * EDIM + lane;
      out[idx] = raw;
      out[idx + third] = sig;
      out[idx + 2 * third] = fmaxf(sig - sg, 0.0f);
    }
  }
}

extern "C" void kernel_launch(void* const* d_in, const int* in_sizes, int n_in,
                              void* d_out, int out_size, void* d_ws, size_t ws_size,
                              hipStream_t stream) {
  const float* H = (const float*)d_in[0];   // [B*S, 4096]
  const float* W = (const float*)d_in[1];   // [4096, 64]
  const float* G = (const float*)d_in[2];   // [64]
  float* out = (float*)d_out;               // 3 x [B*S, 64] concatenated
  __bf16* Wp = (__bf16*)d_ws;               // 512 KB packed (unnormalized) W
  float* partial = (float*)((char*)d_ws + 512 * 1024);  // 64 blocks x 64 cols

  int rows = in_sizes[0] / HDIM;            // 16384
  size_t third = (size_t)out_size / 3;      // 1048576

  pack_w_kernel<<<64, 256, 0, stream>>>(W, Wp, partial);
  gate_main_kernel<<<rows / 16, 512, 0, stream>>>(H, Wp, G, partial, out, third);
}